// Round 10
// baseline (185.299 us; speedup 1.0000x reference)
//
#include <hip/hip_runtime.h>

#define N_ROBOTS 2048
#define EMBED 256
#define M_GROUPS 4096
#define GROUP_K 16
#define N_OBS 64
#define OUT_W 518   // 256 + 256 + 1 + 3 + 1 + 1
#define CAP 128     // bucket capacity per robot (mean 32)
#define NBLOCKS 512 // (256,2) => 2 blocks/CU co-residency, proven by R7

// ws float offsets:
#define WS_RR    0        // rowsum_rr [2048]
#define WS_RO    2048     // rowsum_ro [2048]
#define WS_HG    4096     // hglob_sum [256]
#define WS_CUR   4352     // cursor    [2048] uint  (zeroed in P0)
#define WS_NEQ   6400     // acc_neq   [4096] f32   (zeroed in P0)
#define WS_UQ    10496    // acc_uq    [4096] f32   (zeroed in P0)
#define WS_META  14592    // meta      [4096] uint2 {mask|ucnt<<16, c_neq}
#define WS_BUCK  22784    // bucket    [2048*CAP] int  (ends at 284928)
#define WS_REF   284928   // NEVER written: holds uniform initial word B
#define WS_BARS  284929   // arr[3], rel[3], dep[3] — restored to B each launch

// Poison-invariant grid barrier: works for ANY uniform initial counter value B
// (0 on fresh alloc, 0xAAAAAAAA after harness poison) and restores state == B
// before kernel exit, so graph replays see identical initial conditions.
__device__ inline void gbar(unsigned* bars, unsigned B, int idx, int t) {
    __syncthreads();
    if (t == 0) {
        unsigned* arr = bars + idx;
        unsigned* rel = bars + 3 + idx;
        unsigned* dep = bars + 6 + idx;
        const unsigned e0 = __atomic_load_n(rel, __ATOMIC_RELAXED);
        __threadfence();   // order e0 read before arrival; release phase stores
        const unsigned old = __atomic_fetch_add(arr, 1u, __ATOMIC_RELAXED);
        if (old == B + NBLOCKS - 1u) {     // last arrival releases
            __threadfence();
            __atomic_fetch_add(rel, 1u, __ATOMIC_RELAXED);
        }
        for (int it = 0; it < (1 << 26); ++it) {   // bounded: ~3s max, no 600s hang
            if (__atomic_load_n(rel, __ATOMIC_RELAXED) != e0) break;
            __builtin_amdgcn_s_sleep(2);
        }
        __threadfence();   // acquire
        const unsigned od = __atomic_fetch_add(dep, 1u, __ATOMIC_RELAXED);
        if (od == B + NBLOCKS - 1u) {      // last departer restores state to B
            __atomic_fetch_sub(arr, (unsigned)NBLOCKS, __ATOMIC_RELAXED);
            __atomic_fetch_sub(rel, 1u, __ATOMIC_RELAXED);
            __atomic_fetch_sub(dep, (unsigned)NBLOCKS, __ATOMIC_RELAXED);
        }
    }
    __syncthreads();
}

__global__ __launch_bounds__(256, 2) void mega_kernel(
    const float* __restrict__ h,
    const float* __restrict__ attn_rr,
    const float* __restrict__ attn_ro,
    const float* __restrict__ dist,
    const float* __restrict__ clr,
    const int*   __restrict__ groups,
    float* __restrict__ ws,
    float* __restrict__ out)
{
    const int bid  = blockIdx.x;       // 0..511
    const int t    = threadIdx.x;      // 0..255
    const int w    = t >> 6;           // wave 0..3
    const int lane = t & 63;
    const int gid  = bid * 256 + t;    // 0..131071

    unsigned* bars = (unsigned*)(ws + WS_BARS);
    const unsigned B = __atomic_load_n((unsigned*)(ws + WS_REF), __ATOMIC_RELAXED);

    __shared__ float row[N_ROBOTS];
    __shared__ float red[8];
    __shared__ int   gl[4][2][GROUP_K];
    __shared__ float hg[8][32];

    // ---- P0: zero cursor + acc_neq + acc_uq (10240 floats = 2560 float4) ----
    if (gid < 2560)
        ((float4*)(ws + WS_CUR))[gid] = make_float4(0.f, 0.f, 0.f, 0.f);

    gbar(bars, B, 0, t);

    // ---- P1: occurrence scatter + per-group metadata + h_glob ----
    if (gid < 65536) {
        const int r = groups[gid];
        const unsigned pos = atomicAdd((unsigned*)(ws + WS_CUR) + r, 1u);
        if (pos < CAP) ((int*)(ws + WS_BUCK))[r * CAP + pos] = gid >> 4;
    } else if (gid < 65536 + M_GROUPS) {
        const int m = gid - 65536;
        int g[GROUP_K];
        #pragma unroll
        for (int k = 0; k < GROUP_K; ++k) g[k] = groups[m * GROUP_K + k];
        unsigned mask = 0; int ucnt = 0, ceq = 0;
        #pragma unroll
        for (int i = 0; i < GROUP_K; ++i) {
            bool u = true;
            for (int p = 0; p < i; ++p) if (g[p] == g[i]) { u = false; break; }
            if (u) { mask |= 1u << i; ++ucnt; }
            for (int jj = 0; jj < GROUP_K; ++jj) ceq += (g[i] == g[jj]);
        }
        uint2 v;
        v.x = mask | ((unsigned)ucnt << 16);
        v.y = (unsigned)(GROUP_K * GROUP_K - ceq);   // c_neq
        ((uint2*)(ws + WS_META))[m] = v;
    }
    if (bid >= NBLOCKS - 8) {   // h_glob: last 8 blocks, 32 columns each
        const int bb   = bid - (NBLOCKS - 8);
        const int col  = bb * 32 + (t & 31);
        const int chnk = t >> 5;
        float s2 = 0.f;
        const int r0 = chnk * 256;
        for (int r = r0; r < r0 + 256; ++r)
            s2 += h[(size_t)r * EMBED + col];
        hg[chnk][t & 31] = s2;
        __syncthreads();
        if (t < 32) {
            float tot = 0.f;
            #pragma unroll
            for (int c = 0; c < 8; ++c) tot += hg[c][t];
            ws[WS_HG + bb * 32 + t] = tot;
        }
    }

    gbar(bars, B, 1, t);

    // ---- P2: 4 rows per block — rowsums + bucket accumulation ----
    for (int rr = 0; rr < 4; ++rr) {
        const int r = bid * 4 + rr;
        const float4* row4 = (const float4*)(attn_rr + (size_t)r * N_ROBOTS);
        const float4 a = row4[t];
        const float4 b = row4[t + 256];
        ((float4*)row)[t]       = a;
        ((float4*)row)[t + 256] = b;
        float s  = (a.x + a.y) + (a.z + a.w) + (b.x + b.y) + (b.z + b.w);
        float so = (t < N_OBS) ? attn_ro[(size_t)r * N_OBS + t] : 0.f;
        #pragma unroll
        for (int off = 32; off > 0; off >>= 1) {
            s  += __shfl_down(s,  off);
            so += __shfl_down(so, off);
        }
        if (lane == 0) red[w] = s;
        if (t == 0)    red[4] = so;
        __syncthreads();   // publish row[] + red[]
        if (t == 0) {
            ws[WS_RR + r] = red[0] + red[1] + red[2] + red[3];
            ws[WS_RO + r] = red[4];
        }

        const unsigned cnt = ((const unsigned*)(ws + WS_CUR))[r];
        const unsigned occ = cnt < CAP ? cnt : CAP;
        const int* bucket  = (const int*)(ws + WS_BUCK) + r * CAP;
        const uint2* meta  = (const uint2*)(ws + WS_META);
        const int sg = t >> 4, l = t & 15;   // 16 sub-groups of 16 lanes
        for (unsigned o = sg; o < occ; o += 16) {
            const int m  = bucket[o];
            const int gj = groups[m * GROUP_K + l];
            const unsigned mask = meta[m].x;
            const float v  = row[gj];
            float s0 = (gj != r)          ? v : 0.f;
            float s1 = ((mask >> l) & 1u) ? v : 0.f;
            #pragma unroll
            for (int off = 8; off > 0; off >>= 1) {
                s0 += __shfl_down(s0, off);
                s1 += __shfl_down(s1, off);
            }
            if (l == 0) {
                atomicAdd(ws + WS_NEQ + m, s0);
                atomicAdd(ws + WS_UQ + m,  s1);
            }
        }
        __syncthreads();   // row[] reused next iteration
    }

    gbar(bars, B, 2, t);

    // ---- P3: 8 groups per block (2 per wave) — finalize + stores ----
    if (lane < 32) {
        const int m = bid * 8 + 2 * w + (lane >> 4);
        gl[w][lane >> 4][lane & 15] = groups[(size_t)m * GROUP_K + (lane & 15)];
    }
    __syncthreads();

    const float2* wg2 = (const float2*)(ws + WS_HG);
    const float2 hgl0 = wg2[lane], hgl1 = wg2[lane + 64];

    #pragma unroll
    for (int gg = 0; gg < 2; ++gg) {
        const int m = bid * 8 + 2 * w + gg;
        const int* g = gl[w][gg];

        float2 ha = {0.f, 0.f}, hb = {0.f, 0.f};
        #pragma unroll
        for (int k = 0; k < GROUP_K; ++k) {
            const float2* hr = (const float2*)(h + (size_t)g[k] * EMBED);
            const float2 x = hr[lane];
            const float2 y = hr[lane + 64];
            ha.x += x.x; ha.y += x.y;
            hb.x += y.x; hb.y += y.y;
        }

        float m_rr = 0.f, m_ro = 0.f, m_ds = 0.f, m_cl = 1e30f;
        if (lane < GROUP_K) {
            const int gt = g[lane];
            m_rr = ws[WS_RR + gt];
            m_ro = ws[WS_RO + gt];
            m_ds = dist[gt];
            m_cl = clr[gt];
        }
        #pragma unroll
        for (int off = 8; off > 0; off >>= 1) {
            m_rr += __shfl_down(m_rr, off);
            m_ro += __shfl_down(m_ro, off);
            m_ds += __shfl_down(m_ds, off);
            m_cl  = fminf(m_cl, __shfl_down(m_cl, off));
        }

        const size_t base = (size_t)m * OUT_W;
        float2* out2 = (float2*)(out + base);
        float2 r2;
        r2.x = ha.x * (1.f / GROUP_K); r2.y = ha.y * (1.f / GROUP_K);
        out2[lane] = r2;
        r2.x = hb.x * (1.f / GROUP_K); r2.y = hb.y * (1.f / GROUP_K);
        out2[lane + 64] = r2;
        r2.x = hgl0.x * (1.f / N_ROBOTS); r2.y = hgl0.y * (1.f / N_ROBOTS);
        out2[lane + 128] = r2;
        r2.x = hgl1.x * (1.f / N_ROBOTS); r2.y = hgl1.y * (1.f / N_ROBOTS);
        out2[lane + 192] = r2;

        if (lane == 0) {
            const uint2 mt = ((const uint2*)(ws + WS_META))[m];
            const int   ucnt  = (int)(mt.x >> 16);
            const float c_neq = (float)mt.y;
            const float s_neq = ws[WS_NEQ + m];
            const float s_uq  = ws[WS_UQ + m];
            const float a_in  = s_neq / fmaxf(c_neq, 1.f);
            const float n_out = (float)(N_ROBOTS - ucnt);
            const float a_out = (m_rr - s_uq) / fmaxf((float)GROUP_K * n_out, 1.f);
            const float a_obs = m_ro * (1.f / (GROUP_K * N_OBS));
            out[base + 512] = (float)GROUP_K / 3.0f;
            out[base + 513] = a_in;
            out[base + 514] = a_out;
            out[base + 515] = a_obs;
            out[base + 516] = m_ds * (1.f / GROUP_K);
            out[base + 517] = m_cl;
        }
    }
}

extern "C" void kernel_launch(void* const* d_in, const int* in_sizes, int n_in,
                              void* d_out, int out_size, void* d_ws, size_t ws_size,
                              hipStream_t stream) {
    const float* h       = (const float*)d_in[0];
    const float* attn_rr = (const float*)d_in[1];
    const float* attn_ro = (const float*)d_in[2];
    const float* dist    = (const float*)d_in[3];
    const float* clr     = (const float*)d_in[4];
    const int*   groups  = (const int*)d_in[5];
    float* out = (float*)d_out;
    float* ws  = (float*)d_ws;

    mega_kernel<<<NBLOCKS, 256, 0, stream>>>(h, attn_rr, attn_ro, dist, clr,
                                             groups, ws, out);
}

// Round 11
// 90.833 us; speedup vs baseline: 2.0400x; 2.0400x over previous
//
#include <hip/hip_runtime.h>

#define N_ROBOTS 2048
#define EMBED 256
#define M_GROUPS 4096
#define GROUP_K 16
#define N_OBS 64
#define OUT_W 518
#define NB 512      // blocks; (256,2) co-residency proven in R7/R10
#define RPB 4       // attn_rr rows per block
#define LCAP 512    // local occurrence list capacity (mean 128, +34 sigma)

// ws float offsets
#define WS_RR    0        // rowsum_rr [2048]   plain stores
#define WS_RO    2048     // rowsum_ro [2048]   plain stores
#define WS_HG    4096     // hglob_sum [256]    plain stores
#define WS_NEQ   4352     // acc_neq   [4096]   atomic, zeroed in P0
#define WS_UQ    8448     // acc_uq    [4096]   atomic, zeroed in P0
#define WS_REF   12544    // NEVER written: uniform initial word B
#define WS_BAR   12560    // barrier area (uint offsets below)
// uint offsets in WS_BAR: arrA i*16 (0..255) | midA 256 | relA 272
//   arrB 288+i*16 (..543) | midB 544 | relB 560 | depB 576+i*16 (..831) | midD 832

// Split-counter grid barrier, poison-invariant (any uniform initial word B),
// self-restoring at the LAST barrier's departure so graph replays are identical.
__device__ inline void gbar(unsigned* bar, unsigned B, int last, int bid, int t) {
    __syncthreads();
    if (t == 0) {
        unsigned* arr = bar + (last ? 288 : 0);
        unsigned* mid = bar + (last ? 544 : 256);
        unsigned* rel = bar + (last ? 560 : 272);
        const unsigned e0 = __atomic_load_n(rel, __ATOMIC_RELAXED);
        __threadfence();   // release my phase stores; order e0 before arrival
        const unsigned old = __atomic_fetch_add(&arr[(bid & 15) * 16], 1u, __ATOMIC_RELAXED);
        if (old == B + NB / 16 - 1u) {                 // last of my 32-group
            const unsigned o2 = __atomic_fetch_add(mid, 1u, __ATOMIC_RELAXED);
            if (o2 == B + 15u) { __threadfence(); __atomic_fetch_add(rel, 1u, __ATOMIC_RELAXED); }
        }
        for (int it = 0; it < (1 << 20); ++it) {       // bounded (~0.2s max)
            if (__atomic_load_n(rel, __ATOMIC_RELAXED) != e0) break;
            __builtin_amdgcn_s_sleep(8);
        }
        __threadfence();   // acquire
        if (last) {
            const unsigned od = __atomic_fetch_add(&bar[576 + (bid & 15) * 16], 1u, __ATOMIC_RELAXED);
            if (od == B + NB / 16 - 1u) {
                const unsigned o2 = __atomic_fetch_add(bar + 832, 1u, __ATOMIC_RELAXED);
                if (o2 == B + 15u) {   // last departer: restore ALL state to B
                    for (int i = 0; i < 16; ++i) {
                        __atomic_store_n(&bar[i * 16], B, __ATOMIC_RELAXED);
                        __atomic_store_n(&bar[288 + i * 16], B, __ATOMIC_RELAXED);
                        __atomic_store_n(&bar[576 + i * 16], B, __ATOMIC_RELAXED);
                    }
                    __atomic_store_n(bar + 256, B, __ATOMIC_RELAXED);
                    __atomic_store_n(bar + 272, B, __ATOMIC_RELAXED);
                    __atomic_store_n(bar + 544, B, __ATOMIC_RELAXED);
                    __atomic_store_n(bar + 560, B, __ATOMIC_RELAXED);
                    __atomic_store_n(bar + 832, B, __ATOMIC_RELAXED);
                }
            }
        }
    }
    __syncthreads();
}

__global__ __launch_bounds__(256, 2) void mega_kernel(
    const float* __restrict__ h,
    const float* __restrict__ attn_rr,
    const float* __restrict__ attn_ro,
    const float* __restrict__ dist,
    const float* __restrict__ clr,
    const int*   __restrict__ groups,
    float* __restrict__ ws,
    float* __restrict__ out)
{
    const int bid  = blockIdx.x;      // 0..511
    const int t    = threadIdx.x;     // 0..255
    const int w    = t >> 6;          // wave 0..3
    const int lane = t & 63;

    unsigned* bar = (unsigned*)(ws + WS_BAR);
    const unsigned B = __atomic_load_n((unsigned*)(ws + WS_REF), __ATOMIC_RELAXED);

    __shared__ float rows[RPB][N_ROBOTS];   // 32 KB
    __shared__ float red[4][RPB];
    __shared__ int   list[LCAP];
    __shared__ unsigned lcnt;
    __shared__ float hg[8][32];
    __shared__ int   gl2[4][2][GROUP_K];

    // ---- P0: zero acc_neq + acc_uq (8192 floats = 2048 float4, blocks 0..7) ----
    const int gid = bid * 256 + t;
    if (gid < 2048)
        ((float4*)(ws + WS_NEQ))[gid] = make_float4(0.f, 0.f, 0.f, 0.f);
    if (t == 0) lcnt = 0;

    gbar(bar, B, 0, bid, t);

    // ---- P1: stage rows, rowsums, local scan, occurrence accumulation ----
    #pragma unroll
    for (int rr = 0; rr < RPB; ++rr) {
        const int r = bid * RPB + rr;
        const float4* row4 = (const float4*)(attn_rr + (size_t)r * N_ROBOTS);
        const float4 a = row4[t];
        const float4 b = row4[t + 256];
        ((float4*)rows[rr])[t]       = a;
        ((float4*)rows[rr])[t + 256] = b;
        float s = (a.x + a.y) + (a.z + a.w) + (b.x + b.y) + (b.z + b.w);
        #pragma unroll
        for (int off = 32; off > 0; off >>= 1) s += __shfl_down(s, off);
        if (lane == 0) red[w][rr] = s;
    }
    {   // attn_ro rowsums: wave w owns row bid*RPB+w
        float so = attn_ro[(size_t)(bid * RPB + w) * N_OBS + lane];
        #pragma unroll
        for (int off = 32; off > 0; off >>= 1) so += __shfl_down(so, off);
        if (lane == 0) ws[WS_RO + bid * RPB + w] = so;
    }
    {   // scan groups once; keep occurrences in my 4-row window
        const int4* g4 = (const int4*)groups;
        for (int c = 0; c < 64; ++c) {
            const int idx = c * 256 + t;
            const int4 v = g4[idx];
            const int e0 = idx * 4;
            if ((v.x >> 2) == bid) { unsigned p = atomicAdd(&lcnt, 1u); if (p < LCAP) list[p] = e0; }
            if ((v.y >> 2) == bid) { unsigned p = atomicAdd(&lcnt, 1u); if (p < LCAP) list[p] = e0 + 1; }
            if ((v.z >> 2) == bid) { unsigned p = atomicAdd(&lcnt, 1u); if (p < LCAP) list[p] = e0 + 2; }
            if ((v.w >> 2) == bid) { unsigned p = atomicAdd(&lcnt, 1u); if (p < LCAP) list[p] = e0 + 3; }
        }
    }
    __syncthreads();   // rows, red, list ready
    if (t < RPB)
        ws[WS_RR + bid * RPB + t] = red[0][t] + red[1][t] + red[2][t] + red[3][t];

    {   // occurrence processing: 16 subgroups of 16 lanes
        const int sgid = w * 4 + (lane >> 4);
        const int sb   = (lane >> 4) << 4;
        const int l    = lane & 15;
        const unsigned nocc = lcnt < LCAP ? lcnt : LCAP;
        for (unsigned o = sgid; o < nocc; o += 16) {
            const int e  = list[o];
            const int m  = e >> 4;
            const int gv = groups[m * GROUP_K + l];
            const int r  = __shfl(gv, sb + (e & 15));
            const float v = rows[r & (RPB - 1)][gv];
            int u = 1;
            #pragma unroll
            for (int p = 0; p < 15; ++p) {
                const int gp = __shfl(gv, sb + p);
                if (p < l && gp == gv) u = 0;
            }
            float s0 = (gv != r) ? v : 0.f;
            float s1 = u ? v : 0.f;
            #pragma unroll
            for (int off = 8; off > 0; off >>= 1) {
                s0 += __shfl_down(s0, off);
                s1 += __shfl_down(s1, off);
            }
            if (l == 0) {
                atomicAdd(ws + WS_NEQ + m, s0);
                atomicAdd(ws + WS_UQ + m,  s1);
            }
        }
    }

    if (bid >= NB - 8) {   // h_glob columns on last 8 blocks
        const int bb   = bid - (NB - 8);
        const int col  = bb * 32 + (t & 31);
        const int chnk = t >> 5;
        float s2 = 0.f;
        const int r0 = chnk * 256;
        for (int r2 = r0; r2 < r0 + 256; ++r2)
            s2 += h[(size_t)r2 * EMBED + col];
        hg[chnk][t & 31] = s2;
        __syncthreads();
        if (t < 32) {
            float tot = 0.f;
            #pragma unroll
            for (int c = 0; c < 8; ++c) tot += hg[c][t];
            ws[WS_HG + bb * 32 + t] = tot;
        }
    }

    gbar(bar, B, 1, bid, t);

    // ---- P2: 8 groups per block (2 per wave) — finalize + stores ----
    if (lane < 32) {
        const int m = bid * 8 + w * 2 + (lane >> 4);
        gl2[w][lane >> 4][lane & 15] = groups[(size_t)m * GROUP_K + (lane & 15)];
    }
    __syncthreads();

    const float2* wg2 = (const float2*)(ws + WS_HG);
    const float2 hgl0 = wg2[lane], hgl1 = wg2[lane + 64];

    #pragma unroll
    for (int gg = 0; gg < 2; ++gg) {
        const int m = bid * 8 + w * 2 + gg;
        const int* g = gl2[w][gg];

        float2 ha = {0.f, 0.f}, hb = {0.f, 0.f};
        #pragma unroll
        for (int k = 0; k < GROUP_K; ++k) {
            const float2* hr = (const float2*)(h + (size_t)g[k] * EMBED);
            const float2 x = hr[lane];
            const float2 y = hr[lane + 64];
            ha.x += x.x; ha.y += x.y;
            hb.x += y.x; hb.y += y.y;
        }

        float m_rr = 0.f, m_ro = 0.f, m_ds = 0.f, m_cl = 1e30f, m_u = 0.f, m_ceq = 0.f;
        if (lane < GROUP_K) {
            const int gt = g[lane];
            m_rr = ws[WS_RR + gt];
            m_ro = ws[WS_RO + gt];
            m_ds = dist[gt];
            m_cl = clr[gt];
            int u = 1, ceq = 0;
            #pragma unroll
            for (int p = 0; p < GROUP_K; ++p) {
                const int gp = g[p];
                ceq += (gp == gt);
                if (p < lane && gp == gt) u = 0;
            }
            m_u = (float)u; m_ceq = (float)ceq;
        }
        #pragma unroll
        for (int off = 8; off > 0; off >>= 1) {
            m_rr  += __shfl_down(m_rr,  off);
            m_ro  += __shfl_down(m_ro,  off);
            m_ds  += __shfl_down(m_ds,  off);
            m_cl   = fminf(m_cl, __shfl_down(m_cl, off));
            m_u   += __shfl_down(m_u,   off);
            m_ceq += __shfl_down(m_ceq, off);
        }

        const size_t base = (size_t)m * OUT_W;
        float2* out2 = (float2*)(out + base);
        float2 r2;
        r2.x = ha.x * (1.f / GROUP_K); r2.y = ha.y * (1.f / GROUP_K);
        out2[lane] = r2;
        r2.x = hb.x * (1.f / GROUP_K); r2.y = hb.y * (1.f / GROUP_K);
        out2[lane + 64] = r2;
        r2.x = hgl0.x * (1.f / N_ROBOTS); r2.y = hgl0.y * (1.f / N_ROBOTS);
        out2[lane + 128] = r2;
        r2.x = hgl1.x * (1.f / N_ROBOTS); r2.y = hgl1.y * (1.f / N_ROBOTS);
        out2[lane + 192] = r2;

        if (lane == 0) {
            const float c_neq = 256.f - m_ceq;
            const float s_neq = ws[WS_NEQ + m];
            const float s_uq  = ws[WS_UQ + m];
            const float a_in  = s_neq / fmaxf(c_neq, 1.f);
            const float n_out = (float)N_ROBOTS - m_u;
            const float a_out = (m_rr - s_uq) / fmaxf((float)GROUP_K * n_out, 1.f);
            const float a_obs = m_ro * (1.f / (GROUP_K * N_OBS));
            out[base + 512] = (float)GROUP_K / 3.0f;
            out[base + 513] = a_in;
            out[base + 514] = a_out;
            out[base + 515] = a_obs;
            out[base + 516] = m_ds * (1.f / GROUP_K);
            out[base + 517] = m_cl;
        }
    }
}

extern "C" void kernel_launch(void* const* d_in, const int* in_sizes, int n_in,
                              void* d_out, int out_size, void* d_ws, size_t ws_size,
                              hipStream_t stream) {
    const float* h       = (const float*)d_in[0];
    const float* attn_rr = (const float*)d_in[1];
    const float* attn_ro = (const float*)d_in[2];
    const float* dist    = (const float*)d_in[3];
    const float* clr     = (const float*)d_in[4];
    const int*   groups  = (const int*)d_in[5];
    float* out = (float*)d_out;
    float* ws  = (float*)d_ws;

    mega_kernel<<<NB, 256, 0, stream>>>(h, attn_rr, attn_ro, dist, clr,
                                        groups, ws, out);
}

// Round 12
// 72.720 us; speedup vs baseline: 2.5481x; 1.2491x over previous
//
#include <hip/hip_runtime.h>

#define N_ROBOTS 2048
#define EMBED 256
#define M_GROUPS 4096
#define GROUP_K 16
#define N_OBS 64
#define OUT_W 518
#define NB 512      // 2 blocks/CU co-residency proven R7/R10/R11
#define RPB 4       // attn_rr rows per block
#define LCAP 512    // local occurrence list capacity (mean 128)

// ws float offsets — slots fully rewritten every launch (no zeroing needed):
#define WS_RR    0        // rowsum_rr [2048]           plain stores
#define WS_RO    2048     // rowsum_ro [2048]           plain stores
#define WS_HG    4096     // hglob_sum [256]            plain stores
#define WS_S0    4352     // slot0 [65536] per-occurrence neq-sums (plain stores)
#define WS_S1    69888    // slot1 [65536] per-occurrence uniq-sums (plain stores)
#define WS_BSLOT 135424   // uint arrival slot per block [512] (monotonic +1/launch)
#define WS_REL   135936   // uint release counter (monotonic +1/launch)

__global__ __launch_bounds__(256, 2) void mega_kernel(
    const float* __restrict__ h,
    const float* __restrict__ attn_rr,
    const float* __restrict__ attn_ro,
    const float* __restrict__ dist,
    const float* __restrict__ clr,
    const int*   __restrict__ groups,
    float* __restrict__ ws,
    float* __restrict__ out)
{
    const int bid  = blockIdx.x;      // 0..511
    const int t    = threadIdx.x;     // 0..255
    const int w    = t >> 6;          // wave 0..3
    const int lane = t & 63;

    __shared__ float rows[RPB][N_ROBOTS];   // 32 KB
    __shared__ float red[4][RPB];
    __shared__ int   list[LCAP];
    __shared__ unsigned lcnt;
    __shared__ float hg[32][8];
    __shared__ int   gl2[4][2][GROUP_K];
    __shared__ unsigned Tsh;

    if (t == 0) lcnt = 0;
    __syncthreads();

    // ---- P1a: stage my 4 attn_rr rows in LDS (coalesced) + rowsums ----
    #pragma unroll
    for (int rr = 0; rr < RPB; ++rr) {
        const int r = bid * RPB + rr;
        const float4* row4 = (const float4*)(attn_rr + (size_t)r * N_ROBOTS);
        const float4 a = row4[t];
        const float4 b = row4[t + 256];
        ((float4*)rows[rr])[t]       = a;
        ((float4*)rows[rr])[t + 256] = b;
        float s = (a.x + a.y) + (a.z + a.w) + (b.x + b.y) + (b.z + b.w);
        #pragma unroll
        for (int off = 32; off > 0; off >>= 1) s += __shfl_down(s, off);
        if (lane == 0) red[w][rr] = s;
    }
    {   // attn_ro rowsum: wave w owns row bid*RPB+w
        float so = attn_ro[(size_t)(bid * RPB + w) * N_OBS + lane];
        #pragma unroll
        for (int off = 32; off > 0; off >>= 1) so += __shfl_down(so, off);
        if (lane == 0) ws[WS_RO + bid * RPB + w] = so;
    }

    // ---- P1b: scan groups once (L2-resident), collect my occurrences ----
    {
        const int4* g4 = (const int4*)groups;
        for (int c = 0; c < 64; ++c) {
            const int idx = c * 256 + t;
            const int4 v = g4[idx];
            const int e0 = idx * 4;
            if ((v.x >> 2) == bid) { unsigned p = atomicAdd(&lcnt, 1u); if (p < LCAP) list[p] = e0; }
            if ((v.y >> 2) == bid) { unsigned p = atomicAdd(&lcnt, 1u); if (p < LCAP) list[p] = e0 + 1; }
            if ((v.z >> 2) == bid) { unsigned p = atomicAdd(&lcnt, 1u); if (p < LCAP) list[p] = e0 + 2; }
            if ((v.w >> 2) == bid) { unsigned p = atomicAdd(&lcnt, 1u); if (p < LCAP) list[p] = e0 + 3; }
        }
    }
    __syncthreads();   // rows, red, list ready
    if (t < RPB)
        ws[WS_RR + bid * RPB + t] = red[0][t] + red[1][t] + red[2][t] + red[3][t];

    // ---- P1c: per-occurrence row-slice sums -> dense slots (PLAIN stores) ----
    {
        const int sgid = w * 4 + (lane >> 4);   // subgroup 0..15
        const int sb   = (lane >> 4) << 4;
        const int l    = lane & 15;
        const unsigned nocc = lcnt < LCAP ? lcnt : LCAP;
        for (unsigned o = sgid; o < nocc; o += 16) {
            const int e  = list[o];            // flat index: m*16 + i
            const int m  = e >> 4;
            const int gv = groups[m * GROUP_K + l];      // column member g_l
            const int r  = __shfl(gv, sb + (e & 15));    // row member g_i
            const float v = rows[r & (RPB - 1)][gv];
            int u = 1;
            #pragma unroll
            for (int p = 0; p < 15; ++p) {
                const int gp = __shfl(gv, sb + p);
                if (p < l && gp == gv) u = 0;
            }
            float s0 = (gv != r) ? v : 0.f;    // sum_j row[g_j]*(g_j != g_i)
            float s1 = u ? v : 0.f;            // sum over unique member values
            #pragma unroll
            for (int off = 8; off > 0; off >>= 1) {
                s0 += __shfl_down(s0, off);
                s1 += __shfl_down(s1, off);
            }
            if (l == 0) {                      // exactly one producer per e
                ws[WS_S0 + e] = s0;
                ws[WS_S1 + e] = s1;
            }
        }
    }

    // ---- P1d: h_glob columns on blocks 1..32 (8 cols each) ----
    if (bid >= 1 && bid <= 32) {
        const int bb   = bid - 1;
        const int col  = bb * 8 + (t & 7);
        const int chnk = t >> 3;               // 32 chunks x 64 rows
        float s2 = 0.f;
        const int r0 = chnk * 64;
        for (int r2 = r0; r2 < r0 + 64; ++r2)
            s2 += h[(size_t)r2 * EMBED + col];
        hg[chnk][t & 7] = s2;
        __syncthreads();
        if (t < 8) {
            float tot = 0.f;
            #pragma unroll
            for (int c = 0; c < 32; ++c) tot += hg[c][t];
            ws[WS_HG + bb * 8 + t] = tot;
        }
    }

    // ---- GRID BARRIER: zero returning RMWs, poison/replay-safe, no restore ----
    __syncthreads();
    {
        unsigned* bslot = (unsigned*)(ws + WS_BSLOT);
        unsigned* relp  = (unsigned*)(ws + WS_REL);
        if (bid == 0) {
            if (t == 0) {
                const unsigned tprev = __atomic_load_n(&bslot[0], __ATOMIC_RELAXED);
                __threadfence();                       // release my P1 stores
                __atomic_fetch_add(&bslot[0], 1u, __ATOMIC_RELAXED);  // result unused
                Tsh = tprev + 1u;
            }
            __syncthreads();
            if (w == 0) {                              // wave 0 scans all 512 slots
                const unsigned T = Tsh;
                for (int it = 0; it < (1 << 20); ++it) {
                    int ok = 1;
                    #pragma unroll
                    for (int i = 0; i < 8; ++i) {
                        const unsigned vs = __atomic_load_n(&bslot[lane + 64 * i], __ATOMIC_RELAXED);
                        ok &= (vs == T);
                    }
                    if (__all(ok)) break;
                    __builtin_amdgcn_s_sleep(16);
                }
                if (lane == 0) {
                    __threadfence();
                    __atomic_fetch_add(relp, 1u, __ATOMIC_RELAXED);   // result unused
                }
            }
            __syncthreads();
            if (t == 0) __threadfence();               // acquire
            __syncthreads();
        } else {
            if (t == 0) {
                const unsigned e0 = __atomic_load_n(relp, __ATOMIC_RELAXED);
                __threadfence();                       // order e0 & release P1 stores
                __atomic_fetch_add(&bslot[bid], 1u, __ATOMIC_RELAXED); // result unused
                for (int it = 0; it < (1 << 19); ++it) {
                    if (__atomic_load_n(relp, __ATOMIC_RELAXED) != e0) break;
                    __builtin_amdgcn_s_sleep(32);
                }
                __threadfence();                       // acquire
            }
            __syncthreads();
        }
    }

    // ---- P2: 8 groups per block (2 per wave) — finalize + stores ----
    if (lane < 32) {
        const int m = bid * 8 + w * 2 + (lane >> 4);
        gl2[w][lane >> 4][lane & 15] = groups[(size_t)m * GROUP_K + (lane & 15)];
    }
    __syncthreads();

    const float2* wg2 = (const float2*)(ws + WS_HG);
    const float2 hgl0 = wg2[lane], hgl1 = wg2[lane + 64];

    #pragma unroll
    for (int gg = 0; gg < 2; ++gg) {
        const int m = bid * 8 + w * 2 + gg;
        const int* g = gl2[w][gg];

        float2 ha = {0.f, 0.f}, hb = {0.f, 0.f};
        #pragma unroll
        for (int k = 0; k < GROUP_K; ++k) {
            const float2* hr = (const float2*)(h + (size_t)g[k] * EMBED);
            const float2 x = hr[lane];
            const float2 y = hr[lane + 64];
            ha.x += x.x; ha.y += x.y;
            hb.x += y.x; hb.y += y.y;
        }

        float m_rr = 0.f, m_ro = 0.f, m_ds = 0.f, m_cl = 1e30f;
        float m_u = 0.f, m_ceq = 0.f, m_s0 = 0.f, m_s1 = 0.f;
        if (lane < GROUP_K) {
            const int gt = g[lane];
            m_rr = ws[WS_RR + gt];
            m_ro = ws[WS_RO + gt];
            m_ds = dist[gt];
            m_cl = clr[gt];
            m_s0 = ws[WS_S0 + m * GROUP_K + lane];
            m_s1 = ws[WS_S1 + m * GROUP_K + lane];
            int u = 1, ceq = 0;
            #pragma unroll
            for (int p = 0; p < GROUP_K; ++p) {
                const int gp = g[p];
                ceq += (gp == gt);
                if (p < lane && gp == gt) u = 0;
            }
            m_u = (float)u; m_ceq = (float)ceq;
        }
        #pragma unroll
        for (int off = 8; off > 0; off >>= 1) {
            m_rr  += __shfl_down(m_rr,  off);
            m_ro  += __shfl_down(m_ro,  off);
            m_ds  += __shfl_down(m_ds,  off);
            m_cl   = fminf(m_cl, __shfl_down(m_cl, off));
            m_u   += __shfl_down(m_u,   off);
            m_ceq += __shfl_down(m_ceq, off);
            m_s0  += __shfl_down(m_s0,  off);
            m_s1  += __shfl_down(m_s1,  off);
        }

        const size_t base = (size_t)m * OUT_W;
        float2* out2 = (float2*)(out + base);
        float2 r2;
        r2.x = ha.x * (1.f / GROUP_K); r2.y = ha.y * (1.f / GROUP_K);
        out2[lane] = r2;
        r2.x = hb.x * (1.f / GROUP_K); r2.y = hb.y * (1.f / GROUP_K);
        out2[lane + 64] = r2;
        r2.x = hgl0.x * (1.f / N_ROBOTS); r2.y = hgl0.y * (1.f / N_ROBOTS);
        out2[lane + 128] = r2;
        r2.x = hgl1.x * (1.f / N_ROBOTS); r2.y = hgl1.y * (1.f / N_ROBOTS);
        out2[lane + 192] = r2;

        if (lane == 0) {
            const float c_neq = 256.f - m_ceq;
            const float a_in  = m_s0 / fmaxf(c_neq, 1.f);
            const float n_out = (float)N_ROBOTS - m_u;
            const float a_out = (m_rr - m_s1) / fmaxf((float)GROUP_K * n_out, 1.f);
            const float a_obs = m_ro * (1.f / (GROUP_K * N_OBS));
            out[base + 512] = (float)GROUP_K / 3.0f;
            out[base + 513] = a_in;
            out[base + 514] = a_out;
            out[base + 515] = a_obs;
            out[base + 516] = m_ds * (1.f / GROUP_K);
            out[base + 517] = m_cl;
        }
    }
}

extern "C" void kernel_launch(void* const* d_in, const int* in_sizes, int n_in,
                              void* d_out, int out_size, void* d_ws, size_t ws_size,
                              hipStream_t stream) {
    const float* h       = (const float*)d_in[0];
    const float* attn_rr = (const float*)d_in[1];
    const float* attn_ro = (const float*)d_in[2];
    const float* dist    = (const float*)d_in[3];
    const float* clr     = (const float*)d_in[4];
    const int*   groups  = (const int*)d_in[5];
    float* out = (float*)d_out;
    float* ws  = (float*)d_ws;

    mega_kernel<<<NB, 256, 0, stream>>>(h, attn_rr, attn_ro, dist, clr,
                                        groups, ws, out);
}

// Round 13
// 49.746 us; speedup vs baseline: 3.7249x; 1.4618x over previous
//
#include <hip/hip_runtime.h>

#define N_ROBOTS 2048
#define EMBED 256
#define M_GROUPS 4096
#define GROUP_K 16
#define N_OBS 64
#define OUT_W 518
#define NB 512
#define RPB 4       // attn_rr rows per block
#define LCAP 512    // local occurrence list capacity (mean 128)

// ws float offsets — every consumed slot plain-stored every launch (poison-proof):
#define WS_RR    0        // rowsum_rr [2048]
#define WS_RO    2048     // rowsum_ro [2048]
#define WS_HG    4096     // hglob_sum [256]
#define WS_S0    4352     // slot0 [65536] per-occurrence neq-sums
#define WS_S1    69888    // slot1 [65536] per-occurrence uniq-sums

// K1: rows staging + rowsums + occurrence slots + h_glob. No atomics to global.
__global__ __launch_bounds__(256) void build_kernel(
    const float* __restrict__ h,
    const float* __restrict__ attn_rr,
    const float* __restrict__ attn_ro,
    const int*   __restrict__ groups,
    float* __restrict__ ws)
{
    const int bid  = blockIdx.x;      // 0..511
    const int t    = threadIdx.x;     // 0..255
    const int w    = t >> 6;          // wave 0..3
    const int lane = t & 63;

    __shared__ float rows[RPB][N_ROBOTS];   // 32 KB
    __shared__ float red[4][RPB];
    __shared__ int   list[LCAP];
    __shared__ unsigned lcnt;
    __shared__ float hg[32][8];

    if (t == 0) lcnt = 0;
    __syncthreads();

    // ---- P1a: stage my 4 attn_rr rows in LDS (coalesced) + rowsums ----
    #pragma unroll
    for (int rr = 0; rr < RPB; ++rr) {
        const int r = bid * RPB + rr;
        const float4* row4 = (const float4*)(attn_rr + (size_t)r * N_ROBOTS);
        const float4 a = row4[t];
        const float4 b = row4[t + 256];
        ((float4*)rows[rr])[t]       = a;
        ((float4*)rows[rr])[t + 256] = b;
        float s = (a.x + a.y) + (a.z + a.w) + (b.x + b.y) + (b.z + b.w);
        #pragma unroll
        for (int off = 32; off > 0; off >>= 1) s += __shfl_down(s, off);
        if (lane == 0) red[w][rr] = s;
    }
    {   // attn_ro rowsum: wave w owns row bid*RPB+w
        float so = attn_ro[(size_t)(bid * RPB + w) * N_OBS + lane];
        #pragma unroll
        for (int off = 32; off > 0; off >>= 1) so += __shfl_down(so, off);
        if (lane == 0) ws[WS_RO + bid * RPB + w] = so;
    }

    // ---- P1b: scan groups once (L2-resident), collect my occurrences ----
    {
        const int4* g4 = (const int4*)groups;
        for (int c = 0; c < 64; ++c) {
            const int idx = c * 256 + t;
            const int4 v = g4[idx];
            const int e0 = idx * 4;
            if ((v.x >> 2) == bid) { unsigned p = atomicAdd(&lcnt, 1u); if (p < LCAP) list[p] = e0; }
            if ((v.y >> 2) == bid) { unsigned p = atomicAdd(&lcnt, 1u); if (p < LCAP) list[p] = e0 + 1; }
            if ((v.z >> 2) == bid) { unsigned p = atomicAdd(&lcnt, 1u); if (p < LCAP) list[p] = e0 + 2; }
            if ((v.w >> 2) == bid) { unsigned p = atomicAdd(&lcnt, 1u); if (p < LCAP) list[p] = e0 + 3; }
        }
    }
    __syncthreads();   // rows, red, list ready
    if (t < RPB)
        ws[WS_RR + bid * RPB + t] = red[0][t] + red[1][t] + red[2][t] + red[3][t];

    // ---- P1c: per-occurrence row-slice sums -> dense slots (plain stores) ----
    {
        const int sgid = w * 4 + (lane >> 4);   // subgroup 0..15
        const int sb   = (lane >> 4) << 4;
        const int l    = lane & 15;
        const unsigned nocc = lcnt < LCAP ? lcnt : LCAP;
        for (unsigned o = sgid; o < nocc; o += 16) {
            const int e  = list[o];            // flat index: m*16 + i
            const int m  = e >> 4;
            const int gv = groups[m * GROUP_K + l];      // column member g_l
            const int r  = __shfl(gv, sb + (e & 15));    // row member g_i
            const float v = rows[r & (RPB - 1)][gv];
            int u = 1;
            #pragma unroll
            for (int p = 0; p < 15; ++p) {
                const int gp = __shfl(gv, sb + p);
                if (p < l && gp == gv) u = 0;
            }
            float s0 = (gv != r) ? v : 0.f;    // sum_j row[g_j]*(g_j != g_i)
            float s1 = u ? v : 0.f;            // sum over unique member values
            #pragma unroll
            for (int off = 8; off > 0; off >>= 1) {
                s0 += __shfl_down(s0, off);
                s1 += __shfl_down(s1, off);
            }
            if (l == 0) {                      // exactly one producer per e
                ws[WS_S0 + e] = s0;
                ws[WS_S1 + e] = s1;
            }
        }
    }

    // ---- P1d: h_glob columns on blocks 1..32 (8 cols each) ----
    if (bid >= 1 && bid <= 32) {
        const int bb   = bid - 1;
        const int col  = bb * 8 + (t & 7);
        const int chnk = t >> 3;               // 32 chunks x 64 rows
        float s2 = 0.f;
        const int r0 = chnk * 64;
        for (int r2 = r0; r2 < r0 + 64; ++r2)
            s2 += h[(size_t)r2 * EMBED + col];
        hg[chnk][t & 7] = s2;
        __syncthreads();
        if (t < 8) {
            float tot = 0.f;
            #pragma unroll
            for (int c = 0; c < 32; ++c) tot += hg[c][t];
            ws[WS_HG + bb * 8 + t] = tot;
        }
    }
}

// K2: 8 groups per block (2 per wave) — finalize + stores.
__global__ __launch_bounds__(256) void finalize_kernel(
    const float* __restrict__ h,
    const float* __restrict__ dist,
    const float* __restrict__ clr,
    const int*   __restrict__ groups,
    const float* __restrict__ ws,
    float* __restrict__ out)
{
    const int bid  = blockIdx.x;      // 0..511
    const int t    = threadIdx.x;
    const int w    = t >> 6;
    const int lane = t & 63;

    __shared__ int gl2[4][2][GROUP_K];

    if (lane < 32) {
        const int m = bid * 8 + w * 2 + (lane >> 4);
        gl2[w][lane >> 4][lane & 15] = groups[(size_t)m * GROUP_K + (lane & 15)];
    }
    __syncthreads();

    const float2* wg2 = (const float2*)(ws + WS_HG);
    const float2 hgl0 = wg2[lane], hgl1 = wg2[lane + 64];

    #pragma unroll
    for (int gg = 0; gg < 2; ++gg) {
        const int m = bid * 8 + w * 2 + gg;
        const int* g = gl2[w][gg];

        float2 ha = {0.f, 0.f}, hb = {0.f, 0.f};
        #pragma unroll
        for (int k = 0; k < GROUP_K; ++k) {
            const float2* hr = (const float2*)(h + (size_t)g[k] * EMBED);
            const float2 x = hr[lane];
            const float2 y = hr[lane + 64];
            ha.x += x.x; ha.y += x.y;
            hb.x += y.x; hb.y += y.y;
        }

        float m_rr = 0.f, m_ro = 0.f, m_ds = 0.f, m_cl = 1e30f;
        float m_u = 0.f, m_ceq = 0.f, m_s0 = 0.f, m_s1 = 0.f;
        if (lane < GROUP_K) {
            const int gt = g[lane];
            m_rr = ws[WS_RR + gt];
            m_ro = ws[WS_RO + gt];
            m_ds = dist[gt];
            m_cl = clr[gt];
            m_s0 = ws[WS_S0 + m * GROUP_K + lane];
            m_s1 = ws[WS_S1 + m * GROUP_K + lane];
            int u = 1, ceq = 0;
            #pragma unroll
            for (int p = 0; p < GROUP_K; ++p) {
                const int gp = g[p];
                ceq += (gp == gt);
                if (p < lane && gp == gt) u = 0;
            }
            m_u = (float)u; m_ceq = (float)ceq;
        }
        #pragma unroll
        for (int off = 8; off > 0; off >>= 1) {
            m_rr  += __shfl_down(m_rr,  off);
            m_ro  += __shfl_down(m_ro,  off);
            m_ds  += __shfl_down(m_ds,  off);
            m_cl   = fminf(m_cl, __shfl_down(m_cl, off));
            m_u   += __shfl_down(m_u,   off);
            m_ceq += __shfl_down(m_ceq, off);
            m_s0  += __shfl_down(m_s0,  off);
            m_s1  += __shfl_down(m_s1,  off);
        }

        const size_t base = (size_t)m * OUT_W;
        float2* out2 = (float2*)(out + base);
        float2 r2;
        r2.x = ha.x * (1.f / GROUP_K); r2.y = ha.y * (1.f / GROUP_K);
        out2[lane] = r2;
        r2.x = hb.x * (1.f / GROUP_K); r2.y = hb.y * (1.f / GROUP_K);
        out2[lane + 64] = r2;
        r2.x = hgl0.x * (1.f / N_ROBOTS); r2.y = hgl0.y * (1.f / N_ROBOTS);
        out2[lane + 128] = r2;
        r2.x = hgl1.x * (1.f / N_ROBOTS); r2.y = hgl1.y * (1.f / N_ROBOTS);
        out2[lane + 192] = r2;

        if (lane == 0) {
            const float c_neq = 256.f - m_ceq;
            const float a_in  = m_s0 / fmaxf(c_neq, 1.f);
            const float n_out = (float)N_ROBOTS - m_u;
            const float a_out = (m_rr - m_s1) / fmaxf((float)GROUP_K * n_out, 1.f);
            const float a_obs = m_ro * (1.f / (GROUP_K * N_OBS));
            out[base + 512] = (float)GROUP_K / 3.0f;
            out[base + 513] = a_in;
            out[base + 514] = a_out;
            out[base + 515] = a_obs;
            out[base + 516] = m_ds * (1.f / GROUP_K);
            out[base + 517] = m_cl;
        }
    }
}

extern "C" void kernel_launch(void* const* d_in, const int* in_sizes, int n_in,
                              void* d_out, int out_size, void* d_ws, size_t ws_size,
                              hipStream_t stream) {
    const float* h       = (const float*)d_in[0];
    const float* attn_rr = (const float*)d_in[1];
    const float* attn_ro = (const float*)d_in[2];
    const float* dist    = (const float*)d_in[3];
    const float* clr     = (const float*)d_in[4];
    const int*   groups  = (const int*)d_in[5];
    float* out = (float*)d_out;
    float* ws  = (float*)d_ws;

    build_kernel<<<NB, 256, 0, stream>>>(h, attn_rr, attn_ro, groups, ws);
    finalize_kernel<<<NB, 256, 0, stream>>>(h, dist, clr, groups, ws, out);
}